// Round 24
// baseline (393.535 us; speedup 1.0000x reference)
//
#include <hip/hip_runtime.h>
#include <hip/hip_bf16.h>
#include <math.h>

#define BB 2
#define CCH 128
#define HH 192
#define WW 192
#define KK 9
#define HWs (HH*WW)          // 36864
#define NPIX (BB*HWs)        // 73728

typedef short bf16x8 __attribute__((ext_vector_type(8)));
typedef float f32x4 __attribute__((ext_vector_type(4)));
typedef float f32x16 __attribute__((ext_vector_type(16)));

__device__ __forceinline__ int iclamp(int v, int lo, int hi) {
    return v < lo ? lo : (v > hi ? hi : v);
}
__device__ __forceinline__ unsigned short f2bf(float f) {
    union { __hip_bfloat16 h; unsigned short u; } cvt;
    cvt.h = __float2bfloat16(f);
    return cvt.u;
}
__device__ __forceinline__ float bflo(unsigned u) {   // low bf16 -> f32
    return __uint_as_float(u << 16);
}
__device__ __forceinline__ float bfhi(unsigned u) {   // high bf16 -> f32
    return __uint_as_float(u & 0xFFFF0000u);
}
__device__ __forceinline__ unsigned pkbf(float lo, float hi) {
    return (unsigned)f2bf(lo) | ((unsigned)f2bf(hi) << 16);
}

// ---------------------------------------------------------------------------
// DCN-weight pre-transpose to bf16 with BAKED-IN XOR swizzle:
// Wsw[tap][row=o][col] = W[o][c = col ^ ((row&7)<<3)]  (col in u16 units).
// ---------------------------------------------------------------------------
__global__ void transpose_wsw_kernel(const float* __restrict__ in,
                                     unsigned short* __restrict__ outp) {
    int idx = blockIdx.x * 256 + threadIdx.x;   // 9*128*128 = 147456
    if (idx >= 9 * CCH * CCH) return;
    int col = idx % CCH;
    int row = (idx / CCH) % CCH;                // = o
    int tap = idx / (CCH * CCH);
    int c = col ^ ((row & 7) << 3);
    outp[idx] = f2bf(in[(row * CCH + c) * 9 + tap]);
}

// ---------------------------------------------------------------------------
// om-weight pre-transpose to bf16 with the SAME baked XOR swizzle:
// Womb[tap][o(32)][col] = wom[o][c = col ^ ((o&7)<<3)], o>=27 -> 0.
// ---------------------------------------------------------------------------
__global__ void transpose_womb_kernel(const float* __restrict__ in,
                                      unsigned short* __restrict__ outp) {
    int idx = blockIdx.x * 256 + threadIdx.x;   // 9*32*128 = 36864
    if (idx >= 9 * 32 * CCH) return;
    int col = idx % CCH;
    int o = (idx / CCH) % 32;
    int tap = idx / (CCH * 32);
    int c = col ^ ((o & 7) << 3);
    outp[idx] = (o < 27) ? f2bf(in[(o * CCH + c) * 9 + tap]) : 0;
}

// ---------------------------------------------------------------------------
// NCHW f32 -> NHWC bf16, optional instance-norm + relu.
// ---------------------------------------------------------------------------
__global__ __launch_bounds__(256) void to_nhwc_bf16(
    const float* __restrict__ in, unsigned short* __restrict__ outp,
    const float* __restrict__ mu, const float* __restrict__ rs, int do_relu) {
    __shared__ float tile[CCH][33];
    int blk = blockIdx.x;                 // (b*192 + y)*6 + xt
    int xt = blk % 6;
    int y = (blk / 6) % HH;
    int b = blk / (6 * HH);
    int x0 = xt * 32;
    int t = threadIdx.x;
    int xr = (t & 7) * 4;
    int cr = t >> 3;                      // 0..31
#pragma unroll
    for (int it = 0; it < 4; ++it) {
        int c = it * 32 + cr;
        float4 v = *(const float4*)&in[((size_t)(b * CCH + c) * HH + y) * WW + x0 + xr];
        if (mu != nullptr) {
            float m = mu[b * CCH + c], r = rs[b * CCH + c];
            v.x = (v.x - m) * r; v.y = (v.y - m) * r;
            v.z = (v.z - m) * r; v.w = (v.w - m) * r;
        }
        if (do_relu) {
            v.x = fmaxf(v.x, 0.f); v.y = fmaxf(v.y, 0.f);
            v.z = fmaxf(v.z, 0.f); v.w = fmaxf(v.w, 0.f);
        }
        tile[c][xr] = v.x; tile[c][xr + 1] = v.y;
        tile[c][xr + 2] = v.z; tile[c][xr + 3] = v.w;
    }
    __syncthreads();
    int px = t >> 3;                      // 0..31
    int wp = t & 7;                       // 0..7
    size_t wbase = (((size_t)(b * HH + y)) * WW + x0 + px) * (CCH / 2);
    unsigned* outw = (unsigned*)outp;
#pragma unroll
    for (int it = 0; it < 8; ++it) {
        int ch = it * 16 + wp * 2;
        outw[wbase + it * 8 + wp] = pkbf(tile[ch][px], tile[ch + 1][px]);
    }
}

// ---------------------------------------------------------------------------
// Offset/mask conv via MFMA, all 9 taps' weights resident in LDS (72 KB,
// pre-swizzled -> linear staging), barrier-free k-loop. (r23: om ~40 us.)
// samp layout: [tile=(b*192+y)*3+xt][k][64 px][8]
// ---------------------------------------------------------------------------
__global__ __launch_bounds__(256) void om_mfma_kernel(
    const unsigned short* __restrict__ lob,   // (B,H,W,C) bf16
    const unsigned short* __restrict__ Wob,   // (9,32,128) bf16 pre-swizzled
    const float* __restrict__ bom,            // (27)
    float* __restrict__ samp) {               // (1152,9,64,8)
    __shared__ char smem[73728];              // 72 KB: W (k-loop) / s_om (epi)
    int bid = blockIdx.x;
    int blk = (bid & 7) * 144 + (bid >> 3);   // XCD band swizzle
    int xt = blk % 3;
    int y = (blk / 3) % HH;
    int b = blk / (3 * HH);
    int t = threadIdx.x;
    int l = t & 63, q = l & 15, g = l >> 4, w = t >> 6;
    int px = xt * 64 + w * 16 + q;
    int cb = g * 8;
    int xorq = (q & 7) << 4;                  // LDS read swizzle (bytes)

    // ---- stage all 9 taps of Womb: 73728 B = 256 thr x 18 x 16 B ----
#pragma unroll
    for (int j = 0; j < 18; ++j) {
        uint4 v = *(const uint4*)((const char*)Wob + j * 4096 + t * 16);
        *(uint4*)(smem + j * 4096 + t * 16) = v;
    }
    __syncthreads();

    f32x4 acc0 = (f32x4)0.f, acc1 = (f32x4)0.f;
    for (int k = 0; k < KK; ++k) {
        int ty = k / 3 - 1, tx = k % 3 - 1;
        int yy = y + ty, xx = px + tx;
        bool ok = (yy >= 0 && yy < HH && xx >= 0 && xx < WW);
        int yyc = iclamp(yy, 0, HH - 1), xxc = iclamp(xx, 0, WW - 1);
        const unsigned short* lrow = lob + ((size_t)(b * HH + yyc) * WW + xxc) * CCH;
#pragma unroll
        for (int ch = 0; ch < 4; ++ch) {
            int colb = (ch * 64 + g * 16) ^ xorq;
            bf16x8 a0 = *(const bf16x8*)(smem + (k * 32 + q) * 256 + colb);
            bf16x8 a1 = *(const bf16x8*)(smem + (k * 32 + 16 + q) * 256 + colb);
            bf16x8 bb = *(const bf16x8*)&lrow[ch * 32 + cb];
            if (!ok) bb = (bf16x8)0;
            acc0 = __builtin_amdgcn_mfma_f32_16x16x32_bf16(a0, bb, acc0, 0, 0, 0);
            acc1 = __builtin_amdgcn_mfma_f32_16x16x32_bf16(a1, bb, acc1, 0, 0, 0);
        }
    }

    __syncthreads();   // all waves done reading W before s_om overwrites smem
    float* s_om = (float*)smem;               // [4][16*33]
    float* so = s_om + w * (16 * 33);
#pragma unroll
    for (int r = 0; r < 4; ++r) {
        int o0 = g * 4 + r;               // 0..15, always < 27
        so[q * 33 + o0] = acc0[r] + bom[o0];
        int o1 = 16 + g * 4 + r;          // 16..31
        so[q * 33 + o1] = acc1[r] + ((o1 < 27) ? bom[o1] : 0.f);
    }
    __syncthreads();

    for (int tt = g; tt < 9; tt += 4) {
        float dy = so[q * 33 + 2 * tt];
        float dx = so[q * 33 + 2 * tt + 1];
        float ml = so[q * 33 + 18 + tt];
        float m = 1.0f / (1.0f + __expf(-ml));
        float py = (float)y + (float)(tt / 3 - 1) + dy;
        float pxf = (float)px + (float)(tt % 3 - 1) + dx;
        py = fminf(fmaxf(py, -2.0f), (float)(HH + 1));
        pxf = fminf(fmaxf(pxf, -2.0f), (float)(WW + 1));
        float y0f = floorf(py), x0f = floorf(pxf);
        float ay = py - y0f, ax = pxf - x0f;
        int y0 = (int)y0f, x0i = (int)x0f;
        int y1 = y0 + 1, x1 = x0i + 1;
        bool vy0 = (y0 >= 0 && y0 < HH), vy1 = (y1 >= 0 && y1 < HH);
        bool vx0 = (x0i >= 0 && x0i < WW), vx1 = (x1 >= 0 && x1 < WW);
        int y0c = iclamp(y0, 0, HH - 1), y1c = iclamp(y1, 0, HH - 1);
        int x0c = iclamp(x0i, 0, WW - 1), x1c = iclamp(x1, 0, WW - 1);
        float w00 = (1.0f - ay) * (1.0f - ax) * ((vy0 && vx0) ? m : 0.0f);
        float w01 = (1.0f - ay) * ax * ((vy0 && vx1) ? m : 0.0f);
        float w10 = ay * (1.0f - ax) * ((vy1 && vx0) ? m : 0.0f);
        float w11 = ay * ax * ((vy1 && vx1) ? m : 0.0f);
        float4 s0, s1;
        s0.x = __int_as_float(y0c * WW + x0c);
        s0.y = __int_as_float(y0c * WW + x1c);
        s0.z = __int_as_float(y1c * WW + x0c);
        s0.w = __int_as_float(y1c * WW + x1c);
        s1.x = w00; s1.y = w01; s1.z = w10; s1.w = w11;
        float* sp = samp + (((size_t)blk * 9 + tt) * 64 + w * 16 + q) * 8;
        *(float4*)sp = s0;
        *(float4*)(sp + 4) = s1;
    }
}

// ---------------------------------------------------------------------------
// DCN via 32x32x16 MFMA. r16 config + DOUBLE-BUFFERED W (2x32 KB): staging
// of W_{k+1} goes into the OTHER buffer -> the post-MFMA barrier is removed,
// ONE barrier per tap (18 -> 9 drains). Safety: buf[(k+1)&1] was last read
// in tap k-1 whose end-barrier already passed; writes at tap k are safe.
// Register-safe (r16-style L8/W8 transient batches, no nv[16] prefetch
// state -> no r21 spill). Trade: 64 KB LDS caps 2 blocks/CU (vs ~2.4).
// A: row=lane&31, k=8*(lane>>5)+e. B: col(px)=lane&31, same k.
// C/D: col=lane&31, row=(reg&3)+8*(reg>>2)+4*(lane>>5)  [verified r13].
// ---------------------------------------------------------------------------
__global__ __launch_bounds__(128) void dcn_kernel(
    const unsigned short* __restrict__ xb,    // (B,H,W,C) bf16
    const float* __restrict__ samp,           // (1152,9,64,8)
    const unsigned short* __restrict__ Wsw,   // (9,128,128) bf16 pre-swizzled
    const float* __restrict__ bias,           // (128)
    float* __restrict__ outp) {               // (B,C,H,W)
    __shared__ unsigned short s_w[2][CCH * CCH]; // 64 KB (double buffer)
    int bid = blockIdx.x;                     // 1152
    int blk = (bid & 7) * 144 + (bid >> 3);   // XCD band swizzle (1152 = 8*144)
    int xt = blk % 3;
    int y = (blk / 3) % HH;
    int b = blk / (3 * HH);
    int t = threadIdx.x;                      // 0..127
    int l = t & 63;
    int r32 = l & 31;          // A-row / B-col (pixel) index
    int oct = l >> 5;          // k-octet (0/1)
    int w = t >> 6;            // wave 0..1
    int px = xt * 64 + w * 32 + r32;
    int p_in = w * 32 + r32;
    const unsigned short* xbb = xb + (size_t)b * HWs * CCH;
    const float* rec = samp + (size_t)blk * 9 * 64 * 8;
    const char* wg = (const char*)Wsw;
    int swz = (r32 & 7) << 4;                 // LDS read swizzle (bytes)

    // ---- prologue: stage W0 into buf 0 (256 B/thread, L8/W8 batches) ----
#pragma unroll
    for (int h = 0; h < 2; ++h) {
        uint4 v[8];
#pragma unroll
        for (int j = 0; j < 8; ++j)
            v[j] = *(const uint4*)(wg + (h * 8 + j) * 2048 + t * 16);
#pragma unroll
        for (int j = 0; j < 8; ++j)
            *(uint4*)((char*)s_w[0] + (h * 8 + j) * 2048 + t * 16) = v[j];
    }
    float4 rA = *(const float4*)(rec + (size_t)p_in * 8);
    float4 rB = *(const float4*)(rec + (size_t)p_in * 8 + 4);
    __syncthreads();

    f32x16 acc[4];
#pragma unroll
    for (int ot = 0; ot < 4; ++ot) acc[ot] = (f32x16)0.f;

    for (int k = 0; k < KK; ++k) {
        // ---- MFMA phase: per k-step gather B-frag (8 ch of own pixel),
        //      4 LDS A-reads feed 4 32x32x16 MFMAs (from buf[k&1]) ----
        char* cur = (char*)s_w[k & 1];
        const unsigned short* p00 = xbb + (size_t)__float_as_int(rA.x) * CCH;
        const unsigned short* p01 = xbb + (size_t)__float_as_int(rA.y) * CCH;
        const unsigned short* p10 = xbb + (size_t)__float_as_int(rA.z) * CCH;
        const unsigned short* p11 = xbb + (size_t)__float_as_int(rA.w) * CCH;
#pragma unroll
        for (int ks = 0; ks < 8; ++ks) {
            int c0 = ks * 16 + oct * 8;       // u16 channel base
            uint4 c00 = *(const uint4*)(p00 + c0);
            uint4 c01 = *(const uint4*)(p01 + c0);
            uint4 c10 = *(const uint4*)(p10 + c0);
            uint4 c11 = *(const uint4*)(p11 + c0);
            unsigned bbw[4];
            const unsigned* u00 = (const unsigned*)&c00;
            const unsigned* u01 = (const unsigned*)&c01;
            const unsigned* u10 = (const unsigned*)&c10;
            const unsigned* u11 = (const unsigned*)&c11;
#pragma unroll
            for (int d = 0; d < 4; ++d) {
                float slo = rB.x * bflo(u00[d]) + rB.y * bflo(u01[d]) +
                            rB.z * bflo(u10[d]) + rB.w * bflo(u11[d]);
                float shi = rB.x * bfhi(u00[d]) + rB.y * bfhi(u01[d]) +
                            rB.z * bfhi(u10[d]) + rB.w * bfhi(u11[d]);
                bbw[d] = pkbf(slo, shi);
            }
            uint4 bbu = make_uint4(bbw[0], bbw[1], bbw[2], bbw[3]);
            bf16x8 bb = __builtin_bit_cast(bf16x8, bbu);
            int colb = (ks * 32 + oct * 16) ^ swz;   // swizzled byte col
#pragma unroll
            for (int ot = 0; ot < 4; ++ot) {
                bf16x8 a = *(const bf16x8*)(cur + ((ot * 32 + r32) * 256 + colb));
                acc[ot] = __builtin_amdgcn_mfma_f32_32x32x16_bf16(
                    a, bb, acc[ot], 0, 0, 0);
            }
        }
        if (k < 8) {
            // next records + stage W_{k+1} into the OTHER buffer (no
            // barrier needed before: that buffer's reads ended at tap k-1)
            rA = *(const float4*)(rec + ((size_t)(k + 1) * 64 + p_in) * 8);
            rB = *(const float4*)(rec + ((size_t)(k + 1) * 64 + p_in) * 8 + 4);
            const char* wn = wg + (size_t)(k + 1) * 32768;
            char* nxt = (char*)s_w[(k + 1) & 1];
#pragma unroll
            for (int h = 0; h < 2; ++h) {
                uint4 v[8];
#pragma unroll
                for (int j = 0; j < 8; ++j)
                    v[j] = *(const uint4*)(wn + (h * 8 + j) * 2048 + t * 16);
#pragma unroll
                for (int j = 0; j < 8; ++j)
                    *(uint4*)(nxt + (h * 8 + j) * 2048 + t * 16) = v[j];
            }
        }
        __syncthreads();   // ONE barrier/tap: new W visible + cur reads done
    }

    // ---- epilogue: C/D map col=r32 (pixel), row=(rg&3)+8*(rg>>2)+4*oct ----
#pragma unroll
    for (int ot = 0; ot < 4; ++ot) {
#pragma unroll
        for (int rg = 0; rg < 16; ++rg) {
            int o = ot * 32 + (rg & 3) + 8 * (rg >> 2) + 4 * oct;
            outp[((size_t)(b * CCH + o) * HH + y) * WW + px] =
                acc[ot][rg] + bias[o];
        }
    }
}

// ---------------------------------------------------------------------------
// Per-(b,c) mean / rsqrt(var+eps)
// ---------------------------------------------------------------------------
__global__ __launch_bounds__(256) void stats_kernel(
    const float* __restrict__ d, float* __restrict__ mu,
    float* __restrict__ rs) {
    int ch = blockIdx.x;   // 256
    const float* p = d + (size_t)ch * HWs;
    float s = 0.0f, s2 = 0.0f;
    for (int i = threadIdx.x; i < HWs / 4; i += 256) {
        float4 v = *(const float4*)&p[(size_t)i * 4];
        s += v.x + v.y + v.z + v.w;
        s2 += v.x * v.x + v.y * v.y + v.z * v.z + v.w * v.w;
    }
#pragma unroll
    for (int off = 32; off > 0; off >>= 1) {
        s += __shfl_down(s, off);
        s2 += __shfl_down(s2, off);
    }
    __shared__ float red[8];
    int wid = threadIdx.x >> 6;
    if ((threadIdx.x & 63) == 0) { red[wid] = s; red[4 + wid] = s2; }
    __syncthreads();
    if (threadIdx.x == 0) {
        s = red[0] + red[1] + red[2] + red[3];
        s2 = red[4] + red[5] + red[6] + red[7];
        float m = s / (float)HWs;
        float var = s2 / (float)HWs - m * m;
        mu[ch] = m;
        rs[ch] = rsqrtf(var + 1e-5f);
    }
}

// ---------------------------------------------------------------------------
// out = x + (d - mu)*rs   (elementwise, NCHW)
// ---------------------------------------------------------------------------
__global__ __launch_bounds__(256) void final_kernel(
    const float* __restrict__ x, float* __restrict__ outp,
    const float* __restrict__ mu, const float* __restrict__ rs) {
    size_t i = ((size_t)blockIdx.x * 256 + threadIdx.x) * 4;
    int ch = (int)(i / HWs);
    float4 xv = *(const float4*)&x[i];
    float4 dv = *(const float4*)&outp[i];
    float m = mu[ch], r = rs[ch];
    float4 ov;
    ov.x = xv.x + (dv.x - m) * r;
    ov.y = xv.y + (dv.y - m) * r;
    ov.z = xv.z + (dv.z - m) * r;
    ov.w = xv.w + (dv.w - m) * r;
    *(float4*)&outp[i] = ov;
}

// ---------------------------------------------------------------------------
extern "C" void kernel_launch(void* const* d_in, const int* in_sizes, int n_in,
                              void* d_out, int out_size, void* d_ws,
                              size_t ws_size, hipStream_t stream) {
    (void)in_sizes; (void)n_in; (void)out_size; (void)ws_size;
    const float* x    = (const float*)d_in[0];
    const float* lo   = (const float*)d_in[1];
    const float* wom1 = (const float*)d_in[2];
    const float* bom1 = (const float*)d_in[3];
    const float* w1   = (const float*)d_in[4];
    const float* b1   = (const float*)d_in[5];
    const float* wom2 = (const float*)d_in[6];
    const float* bom2 = (const float*)d_in[7];
    const float* w2   = (const float*)d_in[8];
    const float* b2   = (const float*)d_in[9];
    float* out = (float*)d_out;

    char* wsb = (char*)d_ws;
    unsigned short* xbf  = (unsigned short*)wsb;                 // 18,874,368 B (x, then r1)
    unsigned short* lobf = (unsigned short*)(wsb + 18874368);    // 18,874,368 B
    float* samp = (float*)(wsb + 2 * 18874368);                  // 21,233,664 B
    char* wp = wsb + 2 * 18874368 + 21233664;
    unsigned short* Wb1   = (unsigned short*)wp;                 // 294,912 B
    unsigned short* Wb2   = (unsigned short*)(wp + 294912);
    unsigned short* Womb1 = (unsigned short*)(wp + 2 * 294912);  // 73,728 B
    unsigned short* Womb2 = (unsigned short*)(wp + 2 * 294912 + 73728);
    float* mu1 = (float*)(wp + 2 * 294912 + 2 * 73728);
    float* rs1 = mu1 + 256;
    float* mu2 = rs1 + 256;
    float* rs2 = mu2 + 256;

    // weight pre-transposes (bf16; both W tensors pre-swizzled)
    transpose_wsw_kernel<<<576, 256, 0, stream>>>(w1, Wb1);
    transpose_wsw_kernel<<<576, 256, 0, stream>>>(w2, Wb2);
    transpose_womb_kernel<<<144, 256, 0, stream>>>(wom1, Womb1);
    transpose_womb_kernel<<<144, 256, 0, stream>>>(wom2, Womb2);

    // x, lo -> NHWC bf16
    to_nhwc_bf16<<<2304, 256, 0, stream>>>(x, xbf, nullptr, nullptr, 0);
    to_nhwc_bf16<<<2304, 256, 0, stream>>>(lo, lobf, nullptr, nullptr, 0);

    // ---- block 1 ----
    om_mfma_kernel<<<1152, 256, 0, stream>>>(lobf, Womb1, bom1, samp);
    dcn_kernel<<<1152, 128, 0, stream>>>(xbf, samp, Wb1, b1, out);
    stats_kernel<<<256, 256, 0, stream>>>(out, mu1, rs1);
    to_nhwc_bf16<<<2304, 256, 0, stream>>>(out, xbf, mu1, rs1, 1);  // r1 (reuses xbf)

    // ---- block 2 ----
    om_mfma_kernel<<<1152, 256, 0, stream>>>(lobf, Womb2, bom2, samp);
    dcn_kernel<<<1152, 128, 0, stream>>>(xbf, samp, Wb2, b2, out);
    stats_kernel<<<256, 256, 0, stream>>>(out, mu2, rs2);

    // residual add (in-place on d_out)
    final_kernel<<<9216, 256, 0, stream>>>(x, out, mu2, rs2);
}

// Round 25
// 369.665 us; speedup vs baseline: 1.0646x; 1.0646x over previous
//
#include <hip/hip_runtime.h>
#include <hip/hip_bf16.h>
#include <math.h>

#define BB 2
#define CCH 128
#define HH 192
#define WW 192
#define KK 9
#define HWs (HH*WW)          // 36864
#define NPIX (BB*HWs)        // 73728

typedef short bf16x8 __attribute__((ext_vector_type(8)));
typedef float f32x4 __attribute__((ext_vector_type(4)));
typedef float f32x16 __attribute__((ext_vector_type(16)));

__device__ __forceinline__ int iclamp(int v, int lo, int hi) {
    return v < lo ? lo : (v > hi ? hi : v);
}
__device__ __forceinline__ unsigned short f2bf(float f) {
    union { __hip_bfloat16 h; unsigned short u; } cvt;
    cvt.h = __float2bfloat16(f);
    return cvt.u;
}
__device__ __forceinline__ float bflo(unsigned u) {   // low bf16 -> f32
    return __uint_as_float(u << 16);
}
__device__ __forceinline__ float bfhi(unsigned u) {   // high bf16 -> f32
    return __uint_as_float(u & 0xFFFF0000u);
}
__device__ __forceinline__ unsigned pkbf(float lo, float hi) {
    return (unsigned)f2bf(lo) | ((unsigned)f2bf(hi) << 16);
}

// ---------------------------------------------------------------------------
// DCN-weight pre-transpose to bf16 with BAKED-IN XOR swizzle:
// Wsw[tap][row=o][col] = W[o][c = col ^ ((row&7)<<3)]  (col in u16 units).
// ---------------------------------------------------------------------------
__global__ void transpose_wsw_kernel(const float* __restrict__ in,
                                     unsigned short* __restrict__ outp) {
    int idx = blockIdx.x * 256 + threadIdx.x;   // 9*128*128 = 147456
    if (idx >= 9 * CCH * CCH) return;
    int col = idx % CCH;
    int row = (idx / CCH) % CCH;                // = o
    int tap = idx / (CCH * CCH);
    int c = col ^ ((row & 7) << 3);
    outp[idx] = f2bf(in[(row * CCH + c) * 9 + tap]);
}

// ---------------------------------------------------------------------------
// om-weight pre-transpose to bf16 with the SAME baked XOR swizzle:
// Womb[tap][o(32)][col] = wom[o][c = col ^ ((o&7)<<3)], o>=27 -> 0.
// om stages this linearly into LDS; reads XOR (q&7)<<4 on bytes.
// ---------------------------------------------------------------------------
__global__ void transpose_womb_kernel(const float* __restrict__ in,
                                      unsigned short* __restrict__ outp) {
    int idx = blockIdx.x * 256 + threadIdx.x;   // 9*32*128 = 36864
    if (idx >= 9 * 32 * CCH) return;
    int col = idx % CCH;
    int o = (idx / CCH) % 32;
    int tap = idx / (CCH * 32);
    int c = col ^ ((o & 7) << 3);
    outp[idx] = (o < 27) ? f2bf(in[(o * CCH + c) * 9 + tap]) : 0;
}

// ---------------------------------------------------------------------------
// NCHW f32 -> NHWC bf16, optional instance-norm + relu.
// ---------------------------------------------------------------------------
__global__ __launch_bounds__(256) void to_nhwc_bf16(
    const float* __restrict__ in, unsigned short* __restrict__ outp,
    const float* __restrict__ mu, const float* __restrict__ rs, int do_relu) {
    __shared__ float tile[CCH][33];
    int blk = blockIdx.x;                 // (b*192 + y)*6 + xt
    int xt = blk % 6;
    int y = (blk / 6) % HH;
    int b = blk / (6 * HH);
    int x0 = xt * 32;
    int t = threadIdx.x;
    int xr = (t & 7) * 4;
    int cr = t >> 3;                      // 0..31
#pragma unroll
    for (int it = 0; it < 4; ++it) {
        int c = it * 32 + cr;
        float4 v = *(const float4*)&in[((size_t)(b * CCH + c) * HH + y) * WW + x0 + xr];
        if (mu != nullptr) {
            float m = mu[b * CCH + c], r = rs[b * CCH + c];
            v.x = (v.x - m) * r; v.y = (v.y - m) * r;
            v.z = (v.z - m) * r; v.w = (v.w - m) * r;
        }
        if (do_relu) {
            v.x = fmaxf(v.x, 0.f); v.y = fmaxf(v.y, 0.f);
            v.z = fmaxf(v.z, 0.f); v.w = fmaxf(v.w, 0.f);
        }
        tile[c][xr] = v.x; tile[c][xr + 1] = v.y;
        tile[c][xr + 2] = v.z; tile[c][xr + 3] = v.w;
    }
    __syncthreads();
    int px = t >> 3;                      // 0..31
    int wp = t & 7;                       // 0..7
    size_t wbase = (((size_t)(b * HH + y)) * WW + x0 + px) * (CCH / 2);
    unsigned* outw = (unsigned*)outp;
#pragma unroll
    for (int it = 0; it < 8; ++it) {
        int ch = it * 16 + wp * 2;
        outw[wbase + it * 8 + wp] = pkbf(tile[ch][px], tile[ch + 1][px]);
    }
}

// ---------------------------------------------------------------------------
// Offset/mask conv via MFMA, ALL 9 taps' weights staged in LDS once (72 KB,
// Womb pre-swizzled -> linear staging), then a BARRIER-FREE k-loop: per tap
// just B-loads from lo + LDS A-reads + MFMA. Removes per-wave redundant W
// fetches and all per-tap barriers. LDS aliased with the epilogue transpose
// buffer (barrier separates the two uses).  (r23 measured: om ~40 us.)
// samp layout: [tile=(b*192+y)*3+xt][k][64 px][8]
// ---------------------------------------------------------------------------
__global__ __launch_bounds__(256) void om_mfma_kernel(
    const unsigned short* __restrict__ lob,   // (B,H,W,C) bf16
    const unsigned short* __restrict__ Wob,   // (9,32,128) bf16 pre-swizzled
    const float* __restrict__ bom,            // (27)
    float* __restrict__ samp) {               // (1152,9,64,8)
    __shared__ char smem[73728];              // 72 KB: W (k-loop) / s_om (epi)
    int bid = blockIdx.x;
    int blk = (bid & 7) * 144 + (bid >> 3);   // XCD band swizzle
    int xt = blk % 3;
    int y = (blk / 3) % HH;
    int b = blk / (3 * HH);
    int t = threadIdx.x;
    int l = t & 63, q = l & 15, g = l >> 4, w = t >> 6;
    int px = xt * 64 + w * 16 + q;
    int cb = g * 8;
    int xorq = (q & 7) << 4;                  // LDS read swizzle (bytes)

    // ---- stage all 9 taps of Womb: 73728 B = 256 thr x 18 x 16 B ----
#pragma unroll
    for (int j = 0; j < 18; ++j) {
        uint4 v = *(const uint4*)((const char*)Wob + j * 4096 + t * 16);
        *(uint4*)(smem + j * 4096 + t * 16) = v;
    }
    __syncthreads();

    f32x4 acc0 = (f32x4)0.f, acc1 = (f32x4)0.f;
    for (int k = 0; k < KK; ++k) {
        int ty = k / 3 - 1, tx = k % 3 - 1;
        int yy = y + ty, xx = px + tx;
        bool ok = (yy >= 0 && yy < HH && xx >= 0 && xx < WW);
        int yyc = iclamp(yy, 0, HH - 1), xxc = iclamp(xx, 0, WW - 1);
        const unsigned short* lrow = lob + ((size_t)(b * HH + yyc) * WW + xxc) * CCH;
#pragma unroll
        for (int ch = 0; ch < 4; ++ch) {
            int colb = (ch * 64 + g * 16) ^ xorq;
            bf16x8 a0 = *(const bf16x8*)(smem + (k * 32 + q) * 256 + colb);
            bf16x8 a1 = *(const bf16x8*)(smem + (k * 32 + 16 + q) * 256 + colb);
            bf16x8 bb = *(const bf16x8*)&lrow[ch * 32 + cb];
            if (!ok) bb = (bf16x8)0;
            acc0 = __builtin_amdgcn_mfma_f32_16x16x32_bf16(a0, bb, acc0, 0, 0, 0);
            acc1 = __builtin_amdgcn_mfma_f32_16x16x32_bf16(a1, bb, acc1, 0, 0, 0);
        }
    }

    __syncthreads();   // all waves done reading W before s_om overwrites smem
    float* s_om = (float*)smem;               // [4][16*33]
    float* so = s_om + w * (16 * 33);
#pragma unroll
    for (int r = 0; r < 4; ++r) {
        int o0 = g * 4 + r;               // 0..15, always < 27
        so[q * 33 + o0] = acc0[r] + bom[o0];
        int o1 = 16 + g * 4 + r;          // 16..31
        so[q * 33 + o1] = acc1[r] + ((o1 < 27) ? bom[o1] : 0.f);
    }
    __syncthreads();

    for (int tt = g; tt < 9; tt += 4) {
        float dy = so[q * 33 + 2 * tt];
        float dx = so[q * 33 + 2 * tt + 1];
        float ml = so[q * 33 + 18 + tt];
        float m = 1.0f / (1.0f + __expf(-ml));
        float py = (float)y + (float)(tt / 3 - 1) + dy;
        float pxf = (float)px + (float)(tt % 3 - 1) + dx;
        py = fminf(fmaxf(py, -2.0f), (float)(HH + 1));
        pxf = fminf(fmaxf(pxf, -2.0f), (float)(WW + 1));
        float y0f = floorf(py), x0f = floorf(pxf);
        float ay = py - y0f, ax = pxf - x0f;
        int y0 = (int)y0f, x0i = (int)x0f;
        int y1 = y0 + 1, x1 = x0i + 1;
        bool vy0 = (y0 >= 0 && y0 < HH), vy1 = (y1 >= 0 && y1 < HH);
        bool vx0 = (x0i >= 0 && x0i < WW), vx1 = (x1 >= 0 && x1 < WW);
        int y0c = iclamp(y0, 0, HH - 1), y1c = iclamp(y1, 0, HH - 1);
        int x0c = iclamp(x0i, 0, WW - 1), x1c = iclamp(x1, 0, WW - 1);
        float w00 = (1.0f - ay) * (1.0f - ax) * ((vy0 && vx0) ? m : 0.0f);
        float w01 = (1.0f - ay) * ax * ((vy0 && vx1) ? m : 0.0f);
        float w10 = ay * (1.0f - ax) * ((vy1 && vx0) ? m : 0.0f);
        float w11 = ay * ax * ((vy1 && vx1) ? m : 0.0f);
        float4 s0, s1;
        s0.x = __int_as_float(y0c * WW + x0c);
        s0.y = __int_as_float(y0c * WW + x1c);
        s0.z = __int_as_float(y1c * WW + x0c);
        s0.w = __int_as_float(y1c * WW + x1c);
        s1.x = w00; s1.y = w01; s1.z = w10; s1.w = w11;
        float* sp = samp + (((size_t)blk * 9 + tt) * 64 + w * 16 + q) * 8;
        *(float4*)sp = s0;
        *(float4*)(sp + 4) = s1;
    }
}

// ---------------------------------------------------------------------------
// DCN via 32x32x16 MFMA, 2-wave blocks for cross-block latency hiding.
// MEASURED BEST (r16/r22/r23): dcn 112-118 us. Design space bracketed:
// bigger blocks convoy (r13), more blocks duplicate gathers (r20),
// register prefetch spills (r21), double-buffer halves residency (r24),
// 16x16 MFMA doubles LDS traffic (r7). This is the local optimum.
// A: row=lane&31, k=8*(lane>>5)+e. B: col(px)=lane&31, same k.
// C/D: col=lane&31, row=(reg&3)+8*(reg>>2)+4*(lane>>5)  [verified r13].
// ---------------------------------------------------------------------------
__global__ __launch_bounds__(128) void dcn_kernel(
    const unsigned short* __restrict__ xb,    // (B,H,W,C) bf16
    const float* __restrict__ samp,           // (1152,9,64,8)
    const unsigned short* __restrict__ Wsw,   // (9,128,128) bf16 pre-swizzled
    const float* __restrict__ bias,           // (128)
    float* __restrict__ outp) {               // (B,C,H,W)
    __shared__ unsigned short s_w[CCH * CCH]; // 32 KB
    int bid = blockIdx.x;                     // 1152
    int blk = (bid & 7) * 144 + (bid >> 3);   // XCD band swizzle (1152 = 8*144)
    int xt = blk % 3;
    int y = (blk / 3) % HH;
    int b = blk / (3 * HH);
    int t = threadIdx.x;                      // 0..127
    int l = t & 63;
    int r32 = l & 31;          // A-row / B-col (pixel) index
    int oct = l >> 5;          // k-octet (0/1)
    int w = t >> 6;            // wave 0..1
    int px = xt * 64 + w * 32 + r32;
    int p_in = w * 32 + r32;
    const unsigned short* xbb = xb + (size_t)b * HWs * CCH;
    const float* rec = samp + (size_t)blk * 9 * 64 * 8;
    const char* wg = (const char*)Wsw;
    int swz = (r32 & 7) << 4;                 // LDS read swizzle (bytes)

    // ---- prologue: stage W0 (256 B/thread, load-8/write-8 batches) ----
#pragma unroll
    for (int h = 0; h < 2; ++h) {
        uint4 v[8];
#pragma unroll
        for (int j = 0; j < 8; ++j)
            v[j] = *(const uint4*)(wg + (h * 8 + j) * 2048 + t * 16);
#pragma unroll
        for (int j = 0; j < 8; ++j)
            *(uint4*)((char*)s_w + (h * 8 + j) * 2048 + t * 16) = v[j];
    }
    float4 rA = *(const float4*)(rec + (size_t)p_in * 8);
    float4 rB = *(const float4*)(rec + (size_t)p_in * 8 + 4);
    __syncthreads();

    f32x16 acc[4];
#pragma unroll
    for (int ot = 0; ot < 4; ++ot) acc[ot] = (f32x16)0.f;

    for (int k = 0; k < KK; ++k) {
        // ---- MFMA phase: per k-step gather B-frag (8 ch of own pixel),
        //      4 LDS A-reads feed 4 32x32x16 MFMAs ----
        const unsigned short* p00 = xbb + (size_t)__float_as_int(rA.x) * CCH;
        const unsigned short* p01 = xbb + (size_t)__float_as_int(rA.y) * CCH;
        const unsigned short* p10 = xbb + (size_t)__float_as_int(rA.z) * CCH;
        const unsigned short* p11 = xbb + (size_t)__float_as_int(rA.w) * CCH;
#pragma unroll
        for (int ks = 0; ks < 8; ++ks) {
            int c0 = ks * 16 + oct * 8;       // u16 channel base
            uint4 c00 = *(const uint4*)(p00 + c0);
            uint4 c01 = *(const uint4*)(p01 + c0);
            uint4 c10 = *(const uint4*)(p10 + c0);
            uint4 c11 = *(const uint4*)(p11 + c0);
            unsigned bbw[4];
            const unsigned* u00 = (const unsigned*)&c00;
            const unsigned* u01 = (const unsigned*)&c01;
            const unsigned* u10 = (const unsigned*)&c10;
            const unsigned* u11 = (const unsigned*)&c11;
#pragma unroll
            for (int d = 0; d < 4; ++d) {
                float slo = rB.x * bflo(u00[d]) + rB.y * bflo(u01[d]) +
                            rB.z * bflo(u10[d]) + rB.w * bflo(u11[d]);
                float shi = rB.x * bfhi(u00[d]) + rB.y * bfhi(u01[d]) +
                            rB.z * bfhi(u10[d]) + rB.w * bfhi(u11[d]);
                bbw[d] = pkbf(slo, shi);
            }
            uint4 bbu = make_uint4(bbw[0], bbw[1], bbw[2], bbw[3]);
            bf16x8 bb = __builtin_bit_cast(bf16x8, bbu);
            int colb = (ks * 32 + oct * 16) ^ swz;   // swizzled byte col
#pragma unroll
            for (int ot = 0; ot < 4; ++ot) {
                bf16x8 a = *(const bf16x8*)((char*)s_w +
                            ((ot * 32 + r32) * 256 + colb));
                acc[ot] = __builtin_amdgcn_mfma_f32_32x32x16_bf16(
                    a, bb, acc[ot], 0, 0, 0);
            }
        }
        __syncthreads();               // all reads of s_w done
        if (k < 8) {
            // next records first (queue ahead of staging loads)
            rA = *(const float4*)(rec + ((size_t)(k + 1) * 64 + p_in) * 8);
            rB = *(const float4*)(rec + ((size_t)(k + 1) * 64 + p_in) * 8 + 4);
            // stage W_{k+1}: load-8/write-8 batches (chains broken)
            const char* wn = wg + (size_t)(k + 1) * 32768;
#pragma unroll
            for (int h = 0; h < 2; ++h) {
                uint4 v[8];
#pragma unroll
                for (int j = 0; j < 8; ++j)
                    v[j] = *(const uint4*)(wn + (h * 8 + j) * 2048 + t * 16);
#pragma unroll
                for (int j = 0; j < 8; ++j)
                    *(uint4*)((char*)s_w + (h * 8 + j) * 2048 + t * 16) = v[j];
            }
            __syncthreads();           // new W visible
        }
    }

    // ---- epilogue: C/D map col=r32 (pixel), row=(rg&3)+8*(rg>>2)+4*oct ----
#pragma unroll
    for (int ot = 0; ot < 4; ++ot) {
#pragma unroll
        for (int rg = 0; rg < 16; ++rg) {
            int o = ot * 32 + (rg & 3) + 8 * (rg >> 2) + 4 * oct;
            outp[((size_t)(b * CCH + o) * HH + y) * WW + px] =
                acc[ot][rg] + bias[o];
        }
    }
}

// ---------------------------------------------------------------------------
// Per-(b,c) mean / rsqrt(var+eps)
// ---------------------------------------------------------------------------
__global__ __launch_bounds__(256) void stats_kernel(
    const float* __restrict__ d, float* __restrict__ mu,
    float* __restrict__ rs) {
    int ch = blockIdx.x;   // 256
    const float* p = d + (size_t)ch * HWs;
    float s = 0.0f, s2 = 0.0f;
    for (int i = threadIdx.x; i < HWs / 4; i += 256) {
        float4 v = *(const float4*)&p[(size_t)i * 4];
        s += v.x + v.y + v.z + v.w;
        s2 += v.x * v.x + v.y * v.y + v.z * v.z + v.w * v.w;
    }
#pragma unroll
    for (int off = 32; off > 0; off >>= 1) {
        s += __shfl_down(s, off);
        s2 += __shfl_down(s2, off);
    }
    __shared__ float red[8];
    int wid = threadIdx.x >> 6;
    if ((threadIdx.x & 63) == 0) { red[wid] = s; red[4 + wid] = s2; }
    __syncthreads();
    if (threadIdx.x == 0) {
        s = red[0] + red[1] + red[2] + red[3];
        s2 = red[4] + red[5] + red[6] + red[7];
        float m = s / (float)HWs;
        float var = s2 / (float)HWs - m * m;
        mu[ch] = m;
        rs[ch] = rsqrtf(var + 1e-5f);
    }
}

// ---------------------------------------------------------------------------
// out = x + (d - mu)*rs   (elementwise, NCHW)
// ---------------------------------------------------------------------------
__global__ __launch_bounds__(256) void final_kernel(
    const float* __restrict__ x, float* __restrict__ outp,
    const float* __restrict__ mu, const float* __restrict__ rs) {
    size_t i = ((size_t)blockIdx.x * 256 + threadIdx.x) * 4;
    int ch = (int)(i / HWs);
    float4 xv = *(const float4*)&x[i];
    float4 dv = *(const float4*)&outp[i];
    float m = mu[ch], r = rs[ch];
    float4 ov;
    ov.x = xv.x + (dv.x - m) * r;
    ov.y = xv.y + (dv.y - m) * r;
    ov.z = xv.z + (dv.z - m) * r;
    ov.w = xv.w + (dv.w - m) * r;
    *(float4*)&outp[i] = ov;
}

// ---------------------------------------------------------------------------
extern "C" void kernel_launch(void* const* d_in, const int* in_sizes, int n_in,
                              void* d_out, int out_size, void* d_ws,
                              size_t ws_size, hipStream_t stream) {
    (void)in_sizes; (void)n_in; (void)out_size; (void)ws_size;
    const float* x    = (const float*)d_in[0];
    const float* lo   = (const float*)d_in[1];
    const float* wom1 = (const float*)d_in[2];
    const float* bom1 = (const float*)d_in[3];
    const float* w1   = (const float*)d_in[4];
    const float* b1   = (const float*)d_in[5];
    const float* wom2 = (const float*)d_in[6];
    const float* bom2 = (const float*)d_in[7];
    const float* w2   = (const float*)d_in[8];
    const float* b2   = (const float*)d_in[9];
    float* out = (float*)d_out;

    char* wsb = (char*)d_ws;
    unsigned short* xbf  = (unsigned short*)wsb;                 // 18,874,368 B (x, then r1)
    unsigned short* lobf = (unsigned short*)(wsb + 18874368);    // 18,874,368 B
    float* samp = (float*)(wsb + 2 * 18874368);                  // 21,233,664 B
    char* wp = wsb + 2 * 18874368 + 21233664;
    unsigned short* Wb1   = (unsigned short*)wp;                 // 294,912 B
    unsigned short* Wb2   = (unsigned short*)(wp + 294912);
    unsigned short* Womb1 = (unsigned short*)(wp + 2 * 294912);  // 73,728 B
    unsigned short* Womb2 = (unsigned short*)(wp + 2 * 294912 + 73728);
    float* mu1 = (float*)(wp + 2 * 294912 + 2 * 73728);
    float* rs1 = mu1 + 256;
    float* mu2 = rs1 + 256;
    float* rs2 = mu2 + 256;

    // weight pre-transposes (bf16; both W tensors pre-swizzled)
    transpose_wsw_kernel<<<576, 256, 0, stream>>>(w1, Wb1);
    transpose_wsw_kernel<<<576, 256, 0, stream>>>(w2, Wb2);
    transpose_womb_kernel<<<144, 256, 0, stream>>>(wom1, Womb1);
    transpose_womb_kernel<<<144, 256, 0, stream>>>(wom2, Womb2);

    // x, lo -> NHWC bf16
    to_nhwc_bf16<<<2304, 256, 0, stream>>>(x, xbf, nullptr, nullptr, 0);
    to_nhwc_bf16<<<2304, 256, 0, stream>>>(lo, lobf, nullptr, nullptr, 0);

    // ---- block 1 ----
    om_mfma_kernel<<<1152, 256, 0, stream>>>(lobf, Womb1, bom1, samp);
    dcn_kernel<<<1152, 128, 0, stream>>>(xbf, samp, Wb1, b1, out);
    stats_kernel<<<256, 256, 0, stream>>>(out, mu1, rs1);
    to_nhwc_bf16<<<2304, 256, 0, stream>>>(out, xbf, mu1, rs1, 1);  // r1 (reuses xbf)

    // ---- block 2 ----
    om_mfma_kernel<<<1152, 256, 0, stream>>>(lobf, Womb2, bom2, samp);
    dcn_kernel<<<1152, 128, 0, stream>>>(xbf, samp, Wb2, b2, out);
    stats_kernel<<<256, 256, 0, stream>>>(out, mu2, rs2);

    // residual add (in-place on d_out)
    final_kernel<<<9216, 256, 0, stream>>>(x, out, mu2, rs2);
}